// Round 2
// baseline (2790.400 us; speedup 1.0000x reference)
//
#include <hip/hip_runtime.h>
#include <hip/hip_bf16.h>

#define N_USERS 100000
#define N_ITEMS 150000
#define N_NODES 250000
#define N_EDGES 4000000
#define DIM     64
#define N_ELEM  (N_NODES * DIM)      // 16,000,000
#define U_ELEM  (N_USERS * DIM)      //  6,400,000

// ---------------- helpers ----------------
__device__ __forceinline__ void  store_x(float* p, float v)            { *p = v; }
__device__ __forceinline__ void  store_x(__hip_bfloat16* p, float v)   { *p = __float2bfloat16(v); }
__device__ __forceinline__ float load_x(const float* p)                { return *p; }
__device__ __forceinline__ float load_x(const __hip_bfloat16* p)       { return __bfloat162float(*p); }

// ---------------- dtype probe ----------------
// Reads first 512 u16 words of user_emb as bf16. If data is really bf16
// (N(0,0.1)), all |v| < 1. If data is float32, the low-half words are
// ~uniform bit patterns and some |v| >= 1 (or NaN) with certainty.
// flag = 1 -> inputs are bf16 ; flag = 0 -> inputs are float32.
__global__ void probe_dtype(const unsigned short* __restrict__ ue, int* __restrict__ flag) {
    int lane = threadIdx.x;   // launched with 64 threads
    int bad = 0;
    #pragma unroll
    for (int k = 0; k < 8; ++k) {
        unsigned short u = ue[lane * 8 + k];
        unsigned int b = ((unsigned int)u) << 16;
        float f = __uint_as_float(b);
        f = fabsf(f);
        if (!(f < 1.0f)) bad = 1;   // catches >=1, inf, NaN
    }
    unsigned long long m = __ballot(bad);
    if (lane == 0) flag[0] = (m == 0ULL) ? 1 : 0;
}

// ---------------- init: x = concat(user,item); optional acc / out-acc ----------------
template <typename XT>
__global__ void init_kernel(const void* __restrict__ uev, const void* __restrict__ iev,
                            const int* __restrict__ flag,
                            XT* __restrict__ x,
                            float* __restrict__ acc,     // T1 only (may be null)
                            void* __restrict__ outacc) { // T2/T3 only (may be null)
    int i = blockIdx.x * blockDim.x + threadIdx.x;
    if (i >= N_ELEM) return;
    const int isbf = *flag;
    float v;
    if (i < U_ELEM) {
        v = isbf ? __bfloat162float(((const __hip_bfloat16*)uev)[i])
                 : ((const float*)uev)[i];
    } else {
        int j = i - U_ELEM;
        v = isbf ? __bfloat162float(((const __hip_bfloat16*)iev)[j])
                 : ((const float*)iev)[j];
    }
    store_x(&x[i], v);
    if (acc) acc[i] = v;
    if (outacc) {
        if (isbf) ((__hip_bfloat16*)outacc)[i] = __float2bfloat16(0.25f * v);
        else      ((float*)outacc)[i]          = 0.25f * v;
    }
}

// ---------------- spmm: one wave per edge; lane = dim ----------------
template <typename XT>
__global__ void spmm_kernel(const int* __restrict__ src,
                            const int* __restrict__ dst,
                            const void* __restrict__ valsv,
                            const int* __restrict__ flag,
                            const XT* __restrict__ x,
                            float* __restrict__ xn) {
    int lane  = threadIdx.x & 63;
    int wave  = blockIdx.x * (blockDim.x >> 6) + (threadIdx.x >> 6);
    int nwave = gridDim.x * (blockDim.x >> 6);
    const int isbf = *flag;
    for (int e = wave; e < N_EDGES; e += nwave) {
        int s = src[e];
        int d = dst[e];
        float v = isbf ? __bfloat162float(((const __hip_bfloat16*)valsv)[e])
                       : ((const float*)valsv)[e];
        float xv = load_x(&x[(size_t)s * DIM + lane]);
        atomicAdd(&xn[(size_t)d * DIM + lane], v * xv);
    }
}

// ---------------- T1: acc += xn ----------------
__global__ void acc_add(float* __restrict__ acc, const float* __restrict__ xn) {
    int i = blockIdx.x * blockDim.x + threadIdx.x;
    if (i >= N_ELEM) return;
    acc[i] += xn[i];
}

// ---------------- T2/T3: out += 0.25*xn (out dtype per flag) ----------------
__global__ void out_add(void* __restrict__ outv, const int* __restrict__ flag,
                        const float* __restrict__ xn) {
    int i = blockIdx.x * blockDim.x + threadIdx.x;
    if (i >= N_ELEM) return;
    if (*flag) {
        __hip_bfloat16* o = (__hip_bfloat16*)outv;
        o[i] = __float2bfloat16(__bfloat162float(o[i]) + 0.25f * xn[i]);
    } else {
        float* o = (float*)outv;
        o[i] += 0.25f * xn[i];
    }
}

// ---------------- T3: x = bf16(xn) ----------------
__global__ void x_conv(__hip_bfloat16* __restrict__ x, const float* __restrict__ xn) {
    int i = blockIdx.x * blockDim.x + threadIdx.x;
    if (i >= N_ELEM) return;
    x[i] = __float2bfloat16(xn[i]);
}

// ---------------- T1 final: out = 0.25*acc (dtype per flag) ----------------
__global__ void final_k(const float* __restrict__ acc, void* __restrict__ outv,
                        const int* __restrict__ flag) {
    int i = blockIdx.x * blockDim.x + threadIdx.x;
    if (i >= N_ELEM) return;
    float v = 0.25f * acc[i];
    if (*flag) ((__hip_bfloat16*)outv)[i] = __float2bfloat16(v);
    else       ((float*)outv)[i]          = v;
}

extern "C" void kernel_launch(void* const* d_in, const int* in_sizes, int n_in,
                              void* d_out, int out_size, void* d_ws, size_t ws_size,
                              hipStream_t stream) {
    const int* es = (const int*)d_in[3];
    const int* ed = (const int*)d_in[4];

    char* wsb = (char*)d_ws;
    int* flag = (int*)wsb;
    const size_t FLAGOFF = 256;
    size_t avail = (ws_size > FLAGOFF) ? (ws_size - FLAGOFF) : 0;
    const size_t f32buf = (size_t)N_ELEM * sizeof(float);          // 64 MB
    const size_t bfbuf  = (size_t)N_ELEM * sizeof(__hip_bfloat16); // 32 MB

    const int eb = 256;
    const int egrid = (N_ELEM + eb - 1) / eb;
    const int sgrid = 8192;   // 32768 waves, ~122 edges/wave

    probe_dtype<<<1, 64, 0, stream>>>((const unsigned short*)d_in[0], flag);

    if (avail >= 3 * f32buf) {
        // T1: fp32 x, xn, acc in ws
        float* x   = (float*)(wsb + FLAGOFF);
        float* xn  = x + N_ELEM;
        float* acc = xn + N_ELEM;
        init_kernel<float><<<egrid, eb, 0, stream>>>(d_in[0], d_in[1], flag, x, acc, nullptr);
        for (int l = 0; l < 3; ++l) {
            hipMemsetAsync(xn, 0, f32buf, stream);
            spmm_kernel<float><<<sgrid, eb, 0, stream>>>(es, ed, d_in[2], flag, x, xn);
            acc_add<<<egrid, eb, 0, stream>>>(acc, xn);
            float* t = x; x = xn; xn = t;
        }
        final_k<<<egrid, eb, 0, stream>>>(acc, d_out, flag);
    } else if (avail >= 2 * f32buf) {
        // T2: fp32 x, xn in ws; accumulate into d_out
        float* x  = (float*)(wsb + FLAGOFF);
        float* xn = x + N_ELEM;
        init_kernel<float><<<egrid, eb, 0, stream>>>(d_in[0], d_in[1], flag, x, nullptr, d_out);
        for (int l = 0; l < 3; ++l) {
            hipMemsetAsync(xn, 0, f32buf, stream);
            spmm_kernel<float><<<sgrid, eb, 0, stream>>>(es, ed, d_in[2], flag, x, xn);
            out_add<<<egrid, eb, 0, stream>>>(d_out, flag, xn);
            float* t = x; x = xn; xn = t;
        }
    } else {
        // T3: bf16 x (32 MB) + fp32 xn (64 MB); accumulate into d_out
        __hip_bfloat16* x = (__hip_bfloat16*)(wsb + FLAGOFF);
        float* xn = (float*)(wsb + FLAGOFF + bfbuf);
        init_kernel<__hip_bfloat16><<<egrid, eb, 0, stream>>>(d_in[0], d_in[1], flag, x, nullptr, d_out);
        for (int l = 0; l < 3; ++l) {
            hipMemsetAsync(xn, 0, f32buf, stream);
            spmm_kernel<__hip_bfloat16><<<sgrid, eb, 0, stream>>>(es, ed, d_in[2], flag, x, xn);
            out_add<<<egrid, eb, 0, stream>>>(d_out, flag, xn);
            x_conv<<<egrid, eb, 0, stream>>>(x, xn);
        }
    }
}

// Round 3
// 1139.948 us; speedup vs baseline: 2.4478x; 2.4478x over previous
//
#include <hip/hip_runtime.h>
#include <hip/hip_bf16.h>

#define N_USERS 100000
#define N_ITEMS 150000
#define N_NODES 250000
#define N_EDGES 4000000
#define DIM     64
#define N_ELEM  (N_NODES * DIM)      // 16,000,000
#define U_ELEM  (N_USERS * DIM)      //  6,400,000
#define SCAN_BS 256
#define SCAN_NB ((N_NODES + SCAN_BS - 1) / SCAN_BS)   // 977

// ---------------- helpers ----------------
__device__ __forceinline__ void  store_x(float* p, float v)          { *p = v; }
__device__ __forceinline__ void  store_x(__hip_bfloat16* p, float v) { *p = __float2bfloat16(v); }
__device__ __forceinline__ float load_x(const float* p)              { return *p; }
__device__ __forceinline__ float load_x(const __hip_bfloat16* p)     { return __bfloat162float(*p); }

// ---------------- dtype probe (flag=1 -> bf16 inputs, 0 -> fp32) ----------------
__global__ void probe_dtype(const unsigned short* __restrict__ ue, int* __restrict__ flag) {
    int lane = threadIdx.x;   // 64 threads
    int bad = 0;
    #pragma unroll
    for (int k = 0; k < 8; ++k) {
        unsigned int b = ((unsigned int)ue[lane * 8 + k]) << 16;
        float f = fabsf(__uint_as_float(b));
        if (!(f < 1.0f)) bad = 1;
    }
    unsigned long long m = __ballot(bad);
    if (lane == 0) flag[0] = (m == 0ULL) ? 1 : 0;
}

// ---------------- CSR build ----------------
__global__ void hist_kernel(const int* __restrict__ dst, int* __restrict__ row_ptr) {
    int e = blockIdx.x * blockDim.x + threadIdx.x;
    if (e < N_EDGES) atomicAdd(&row_ptr[dst[e] + 1], 1);
}

// inclusive scan of a[0..N_NODES-1] (a = row_ptr+1), per-block stage
__global__ void scan_block(int* __restrict__ a, int* __restrict__ bsums) {
    __shared__ int sh[SCAN_BS];
    int gid = blockIdx.x * SCAN_BS + threadIdx.x;
    sh[threadIdx.x] = (gid < N_NODES) ? a[gid] : 0;
    __syncthreads();
    for (int off = 1; off < SCAN_BS; off <<= 1) {
        int t = (threadIdx.x >= off) ? sh[threadIdx.x - off] : 0;
        __syncthreads();
        sh[threadIdx.x] += t;
        __syncthreads();
    }
    if (gid < N_NODES) a[gid] = sh[threadIdx.x];
    if (threadIdx.x == SCAN_BS - 1) bsums[blockIdx.x] = sh[threadIdx.x];
}

__global__ void scan_tops(int* __restrict__ bsums) {
    __shared__ int sh[1024];
    sh[threadIdx.x] = (threadIdx.x < SCAN_NB) ? bsums[threadIdx.x] : 0;
    __syncthreads();
    for (int off = 1; off < 1024; off <<= 1) {
        int t = (threadIdx.x >= off) ? sh[threadIdx.x - off] : 0;
        __syncthreads();
        sh[threadIdx.x] += t;
        __syncthreads();
    }
    if (threadIdx.x < SCAN_NB) bsums[threadIdx.x] = sh[threadIdx.x];
}

__global__ void finalize_rows(int* __restrict__ row_ptr, const int* __restrict__ bsums) {
    int i = blockIdx.x * blockDim.x + threadIdx.x;   // element i of a[] == row_ptr[i+1]
    if (i >= N_NODES) return;
    int b = i / SCAN_BS;
    if (b > 0) row_ptr[i + 1] += bsums[b - 1];
    if (i == 0) row_ptr[0] = 0;
}

__global__ void copy_cursor(const int* __restrict__ row_ptr, int* __restrict__ cursor) {
    int i = blockIdx.x * blockDim.x + threadIdx.x;
    if (i < N_NODES) cursor[i] = row_ptr[i];
}

template <typename VT>
__global__ void scatter_kernel(const int* __restrict__ src, const int* __restrict__ dst,
                               const void* __restrict__ valsv, const int* __restrict__ flag,
                               int* __restrict__ cursor,
                               int* __restrict__ ssrc, VT* __restrict__ sval) {
    int e = blockIdx.x * blockDim.x + threadIdx.x;
    if (e >= N_EDGES) return;
    int d = dst[e];
    int pos = atomicAdd(&cursor[d], 1);
    float v = (*flag) ? __bfloat162float(((const __hip_bfloat16*)valsv)[e])
                      : ((const float*)valsv)[e];
    ssrc[pos] = src[e];
    store_x(&sval[pos], v);
}

// ---------------- init: x = concat(user,item); acc (T1) or out-acc (T2/T3) ----------------
template <typename XT>
__global__ void init_kernel(const void* __restrict__ uev, const void* __restrict__ iev,
                            const int* __restrict__ flag,
                            XT* __restrict__ x,
                            float* __restrict__ acc,
                            void* __restrict__ outacc) {
    int i = blockIdx.x * blockDim.x + threadIdx.x;
    if (i >= N_ELEM) return;
    const int isbf = *flag;
    float v;
    if (i < U_ELEM) {
        v = isbf ? __bfloat162float(((const __hip_bfloat16*)uev)[i]) : ((const float*)uev)[i];
    } else {
        int j = i - U_ELEM;
        v = isbf ? __bfloat162float(((const __hip_bfloat16*)iev)[j]) : ((const float*)iev)[j];
    }
    store_x(&x[i], v);
    if (acc) acc[i] = v;
    if (outacc) {
        if (isbf) ((__hip_bfloat16*)outacc)[i] = __float2bfloat16(0.25f * v);
        else      ((float*)outacc)[i]          = 0.25f * v;
    }
}

// ---------------- CSR SpMM: one wave per dst node, lane = dim ----------------
template <typename XT, typename VT>
__global__ void spmm_csr(const int* __restrict__ row_ptr,
                         const int* __restrict__ ssrc,
                         const VT* __restrict__ sval,
                         const XT* __restrict__ x,
                         XT* __restrict__ xn,
                         float* __restrict__ acc,      // T1 mode if non-null
                         void* __restrict__ outv,      // T2/T3 RMW target, or T1 final target
                         const int* __restrict__ flag,
                         int last) {
    int lane = threadIdx.x & 63;
    int w = (blockIdx.x * blockDim.x + threadIdx.x) >> 6;
    if (w >= N_NODES) return;
    int beg = row_ptr[w], end = row_ptr[w + 1];
    float s = 0.f;
    int e = beg;
    for (; e + 4 <= end; e += 4) {
        int i0 = ssrc[e], i1 = ssrc[e + 1], i2 = ssrc[e + 2], i3 = ssrc[e + 3];
        float v0 = load_x(&sval[e]),     v1 = load_x(&sval[e + 1]);
        float v2 = load_x(&sval[e + 2]), v3 = load_x(&sval[e + 3]);
        float a0 = load_x(&x[(size_t)i0 * DIM + lane]);
        float a1 = load_x(&x[(size_t)i1 * DIM + lane]);
        float a2 = load_x(&x[(size_t)i2 * DIM + lane]);
        float a3 = load_x(&x[(size_t)i3 * DIM + lane]);
        s += v0 * a0; s += v1 * a1; s += v2 * a2; s += v3 * a3;
    }
    for (; e < end; ++e) s += load_x(&sval[e]) * load_x(&x[(size_t)ssrc[e] * DIM + lane]);

    size_t o = (size_t)w * DIM + lane;
    if (acc) {
        if (!last) {
            store_x(&xn[o], s);
            acc[o] += s;
        } else {
            float r = 0.25f * (acc[o] + s);
            if (*flag) ((__hip_bfloat16*)outv)[o] = __float2bfloat16(r);
            else       ((float*)outv)[o]          = r;
        }
    } else {
        if (!last) store_x(&xn[o], s);
        if (*flag) {
            __hip_bfloat16* ob = (__hip_bfloat16*)outv;
            ob[o] = __float2bfloat16(__bfloat162float(ob[o]) + 0.25f * s);
        } else {
            float* of = (float*)outv;
            of[o] += 0.25f * s;
        }
    }
}

// ---------------- host ----------------
static inline size_t align256(size_t x) { return (x + 255) & ~(size_t)255; }

extern "C" void kernel_launch(void* const* d_in, const int* in_sizes, int n_in,
                              void* d_out, int out_size, void* d_ws, size_t ws_size,
                              hipStream_t stream) {
    const int* es = (const int*)d_in[3];
    const int* ed = (const int*)d_in[4];

    char* wsb = (char*)d_ws;
    size_t off = 0;
    int* flag    = (int*)wsb;                 off = align256(off + sizeof(int));
    int* row_ptr = (int*)(wsb + off);         off = align256(off + (size_t)(N_NODES + 1) * 4);
    int* cursor  = (int*)(wsb + off);         off = align256(off + (size_t)N_NODES * 4);
    int* bsums   = (int*)(wsb + off);         off = align256(off + (size_t)SCAN_NB * 4);
    int* ssrc    = (int*)(wsb + off);         off = align256(off + (size_t)N_EDGES * 4);
    size_t val_off = off;                     // VT-sized, reserved below per tier

    const size_t f32buf = (size_t)N_ELEM * sizeof(float);          // 64 MB
    const size_t bfbuf  = (size_t)N_ELEM * sizeof(__hip_bfloat16); // 32 MB

    const int eb = 256;
    const int egrid = (N_ELEM + eb - 1) / eb;
    const int ggrid = (N_EDGES + eb - 1) / eb;            // 15625
    const int ngrid = (N_NODES + eb - 1) / eb;            // 977
    const int sgrid = (N_NODES + 3) / 4;                  // 62500 blocks, 4 waves each

    // ---- common prologue: probe + CSR build (VT chosen per tier) ----
    probe_dtype<<<1, 64, 0, stream>>>((const unsigned short*)d_in[0], flag);
    hipMemsetAsync(row_ptr, 0, (size_t)(N_NODES + 1) * 4, stream);
    hist_kernel<<<ggrid, eb, 0, stream>>>(ed, row_ptr);
    scan_block<<<SCAN_NB, SCAN_BS, 0, stream>>>(row_ptr + 1, bsums);
    scan_tops<<<1, 1024, 0, stream>>>(bsums);
    finalize_rows<<<ngrid, eb, 0, stream>>>(row_ptr, bsums);
    copy_cursor<<<ngrid, eb, 0, stream>>>(row_ptr, cursor);

    // tier thresholds measured from end of ssrc (val_off)
    size_t need_t1 = val_off + align256((size_t)N_EDGES * 4) + 3 * f32buf;  // ~226 MB
    size_t need_t2 = val_off + align256((size_t)N_EDGES * 4) + 2 * f32buf;  // ~162 MB

    if (ws_size >= need_t1) {
        // T1: fp32 sval; fp32 x, xn, acc; out written in last spmm
        float* sval = (float*)(wsb + val_off);
        size_t boff = val_off + align256((size_t)N_EDGES * 4);
        float* x   = (float*)(wsb + boff);
        float* xn  = x + N_ELEM;
        float* acc = xn + N_ELEM;
        scatter_kernel<float><<<ggrid, eb, 0, stream>>>(es, ed, d_in[2], flag, cursor, ssrc, sval);
        init_kernel<float><<<egrid, eb, 0, stream>>>(d_in[0], d_in[1], flag, x, acc, nullptr);
        spmm_csr<float, float><<<sgrid, eb, 0, stream>>>(row_ptr, ssrc, sval, x,  xn, acc, nullptr, flag, 0);
        spmm_csr<float, float><<<sgrid, eb, 0, stream>>>(row_ptr, ssrc, sval, xn, x,  acc, nullptr, flag, 0);
        spmm_csr<float, float><<<sgrid, eb, 0, stream>>>(row_ptr, ssrc, sval, x,  xn, acc, d_out,   flag, 1);
    } else if (ws_size >= need_t2) {
        // T2: fp32 sval; fp32 x, xn; accumulate into d_out (RMW)
        float* sval = (float*)(wsb + val_off);
        size_t boff = val_off + align256((size_t)N_EDGES * 4);
        float* x  = (float*)(wsb + boff);
        float* xn = x + N_ELEM;
        scatter_kernel<float><<<ggrid, eb, 0, stream>>>(es, ed, d_in[2], flag, cursor, ssrc, sval);
        init_kernel<float><<<egrid, eb, 0, stream>>>(d_in[0], d_in[1], flag, x, nullptr, d_out);
        spmm_csr<float, float><<<sgrid, eb, 0, stream>>>(row_ptr, ssrc, sval, x,  xn, nullptr, d_out, flag, 0);
        spmm_csr<float, float><<<sgrid, eb, 0, stream>>>(row_ptr, ssrc, sval, xn, x,  nullptr, d_out, flag, 0);
        spmm_csr<float, float><<<sgrid, eb, 0, stream>>>(row_ptr, ssrc, sval, x,  xn, nullptr, d_out, flag, 1);
    } else {
        // T3: bf16 sval; bf16 x, xn; accumulate into d_out (RMW)  (~90 MB)
        __hip_bfloat16* sval = (__hip_bfloat16*)(wsb + val_off);
        size_t boff = val_off + align256((size_t)N_EDGES * 2);
        __hip_bfloat16* x  = (__hip_bfloat16*)(wsb + boff);
        __hip_bfloat16* xn = x + N_ELEM;
        scatter_kernel<__hip_bfloat16><<<ggrid, eb, 0, stream>>>(es, ed, d_in[2], flag, cursor, ssrc, sval);
        init_kernel<__hip_bfloat16><<<egrid, eb, 0, stream>>>(d_in[0], d_in[1], flag, x, nullptr, d_out);
        spmm_csr<__hip_bfloat16, __hip_bfloat16><<<sgrid, eb, 0, stream>>>(row_ptr, ssrc, sval, x,  xn, nullptr, d_out, flag, 0);
        spmm_csr<__hip_bfloat16, __hip_bfloat16><<<sgrid, eb, 0, stream>>>(row_ptr, ssrc, sval, xn, x,  nullptr, d_out, flag, 0);
        spmm_csr<__hip_bfloat16, __hip_bfloat16><<<sgrid, eb, 0, stream>>>(row_ptr, ssrc, sval, x,  xn, nullptr, d_out, flag, 1);
    }
}